// Round 6
// baseline (133.412 us; speedup 1.0000x reference)
//
#include <hip/hip_runtime.h>
#include <math.h>

#define STR   36                 // padded row stride (floats): 144 B, 16B-aligned, bank rot 4/row
#define RPAD  24                 // row capacity: 3 chunks of 8 (span guarantee <= 22)
#define PLANE (RPAD * STR)       // 864 floats per channel plane
#define ITERS 8                  // 8 chunks of 4 channels per block
// LDS: 4 planes x 864 x 4B = 13.5 KB -> 8 blocks/CU (wave-limited, full occupancy).
// Layout: element (row,x) at row*36+x -> bank (4*row+x)&31: same x on different
// rows conflict-free within any 8-row window; x,x+1 contiguous -> ds_read2_b32.

__global__ __launch_bounds__(256, 8) void roialign_kernel(
    const float* __restrict__ feat, const float* __restrict__ bbox,
    float* __restrict__ out) {
  __shared__ float lds[4 * PLANE];
  __shared__ int   sxa[14];                 // x0f in 0..30
  __shared__ float swx[14];                 // xs - x0f  (x=31 edge -> wx=1, exact)
  __shared__ int   sy0a[14], sy1a[14];      // row offsets pre-scaled by STR
  __shared__ float swy[14];

  const int blk = blockIdx.x;
  const int n   = blk >> 3;                 // box
  const int C0  = (blk & 7) * 32;           // first channel of this block's 32
  const int t   = threadIdx.x;
  const int wv  = t >> 6;                   // wave = channel within chunk
  const int ln  = t & 63;

  const float bx1 = bbox[n * 4 + 0];
  const float by1 = bbox[n * 4 + 1];
  const float bx2 = bbox[n * 4 + 2];
  const float by2 = bbox[n * 4 + 3];
  const float xstep = (bx2 - bx1) * (1.0f / 14.0f);
  const float ystep = (by2 - by1) * (1.0f / 14.0f);

  // ---- row range touched by the 14 y samples (block-uniform) ----
  const int ylo = min(max((int)floorf(by1), 0), 31);
  const float ys13 = by1 + 13.0f * ystep;
  int yhi = min(min(max((int)floorf(ys13), 0), 31) + 1, 31);
  yhi = min(yhi, ylo + (RPAD - 1));         // defensive
  const int R = yhi - ylo + 1;              // rows to stage (<= 22)

  // ---- coordinate tables, once per block ----
  if (t < 14) {
    float xs = bx1 + (float)t * xstep;
    int x0i = (int)fminf(fmaxf(floorf(xs), 0.0f), 31.0f);
    int x0f = min(x0i, 30);                 // pair (x0f, x0f+1) always valid
    sxa[t] = x0f;
    swx[t] = xs - (float)x0f;               // ==1 at the x=31 edge (exact)
  } else if (t < 28) {
    int g = t - 14;
    float yv = by1 + (float)g * ystep;
    float y0 = fminf(fmaxf(floorf(yv), 0.0f), 31.0f);
    int y0i = (int)y0;
    int y1i = min(y0i + 1, 31);
    y0i = min(max(y0i, ylo), yhi);
    y1i = min(max(y1i, ylo), yhi);
    sy0a[g] = (y0i - ylo) * STR;
    sy1a[g] = (y1i - ylo) * STR;
    swy[g] = yv - y0;
  }

  // ---- staging machinery: wave wv stages one channel per iteration ----
  const int rch = ln >> 3;                  // row within 8-row chunk
  const int q   = ln & 7;                   // float4 group within row
  const float* gsrc0 =
      feat + (size_t)n * (256 * 1024) + (size_t)ylo * 32 + q * 4;
  float4 regs[3];

  const int sy = ln / 7;                    // output coords (lanes < 49)
  const int sx = ln - sy * 7;
  const float* plane = lds + wv * PLANE;

  // prologue: issue loads for chunk 0
  {
    const float* sb = gsrc0 + (size_t)(C0 + wv) * 1024;
#pragma unroll
    for (int k = 0; k < 3; ++k)
      if (k * 8 < R) {
        int srow = min(k * 8 + rch, R - 1);
        regs[k] = *(const float4*)(sb + srow * 32);
      }
  }

  for (int it = 0; it < ITERS; ++it) {
    // write staged registers to LDS (padded layout)
    {
      float* db = lds + wv * PLANE + q * 4;
#pragma unroll
      for (int k = 0; k < 3; ++k)
        if (k * 8 < R) {
          int row = k * 8 + rch;
          *(float4*)(db + row * STR) = regs[k];
        }
    }
    __syncthreads();                        // tile ready

    // prefetch next chunk's channel while computing this one (T14)
    if (it + 1 < ITERS) {
      const float* sb = gsrc0 + (size_t)(C0 + (it + 1) * 4 + wv) * 1024;
#pragma unroll
      for (int k = 0; k < 3; ++k)
        if (k * 8 < R) {
          int srow = min(k * 8 + rch, R - 1);
          regs[k] = *(const float4*)(sb + srow * 32);
        }
    }

    // compute: lane < 49 -> one 7x7 output of channel (C0 + it*4 + wv)
    if (ln < 49) {
      float m = -INFINITY;
#pragma unroll
      for (int i = 0; i < 2; ++i) {
        const int gy = 2 * sy + i;
        const float* r0 = plane + sy0a[gy];
        const float* r1 = plane + sy1a[gy];
        const float wy = swy[gy];
#pragma unroll
        for (int j = 0; j < 2; ++j) {
          const int gx = 2 * sx + j;
          const int x  = sxa[gx];
          const float wx = swx[gx];
          const float* p0 = r0 + x;         // -> ds_read2_b32 offset1:1
          const float* p1 = r1 + x;
          float v00 = p0[0], v01 = p0[1];
          float v10 = p1[0], v11 = p1[1];
          float top = fmaf(wx, v01 - v00, v00);
          float bot = fmaf(wx, v11 - v10, v10);
          m = fmaxf(m, fmaf(wy, bot - top, top));
        }
      }
      out[((size_t)(n * 256 + C0 + it * 4 + wv)) * 49 + ln] = m;
    }
    __syncthreads();                        // tile consumed before overwrite
  }
}

extern "C" void kernel_launch(void* const* d_in, const int* in_sizes, int n_in,
                              void* d_out, int out_size, void* d_ws, size_t ws_size,
                              hipStream_t stream) {
  const float* feat = (const float*)d_in[0];
  const float* bbox = (const float*)d_in[1];
  float* out = (float*)d_out;
  dim3 grid(512 * 8);                       // one block per (box, 32-channel group)
  roialign_kernel<<<grid, 256, 0, stream>>>(feat, bbox, out);
}

// Round 7
// 117.664 us; speedup vs baseline: 1.1338x; 1.1338x over previous
//
#include <hip/hip_runtime.h>
#include <math.h>

#define STR   36                 // padded row stride (floats): 144 B, 16B-aligned
#define RPAD  22                 // row capacity (span guarantee <= 22)
#define PLANE (RPAD * STR)       // 792 floats per channel plane
// LDS: 8 planes x 792 x 4B = 25.3 KB -> 6 blocks/CU (24 waves/CU).
// Row rotation of 4 banks/row (36 = 32+4) kills same-x cross-row conflicts;
// x,x+1 contiguous -> ds_read2_b32 (8 LDS instrs per 7x7 tile, was 16).
// One-shot block (round-5 structure): stage -> barrier -> compute -> done.

__global__ __launch_bounds__(256, 6) void roialign_kernel(
    const float* __restrict__ feat, const float* __restrict__ bbox,
    float* __restrict__ out) {
  __shared__ float lds[8 * PLANE];
  __shared__ int   sxa[14];                 // x0 (always <= 30)
  __shared__ float swx[14];
  __shared__ int   sy0a[14], sy1a[14];      // row offsets pre-scaled by STR
  __shared__ float swy[14];

  const int blk = blockIdx.x;
  const int n   = blk >> 5;                 // box
  const int c0  = (blk & 31) * 8;           // first of this block's 8 channels
  const int t   = threadIdx.x;
  const int wv  = t >> 6;                   // wave owns channels c0+2wv, c0+2wv+1
  const int ln  = t & 63;

  const float bx1 = bbox[n * 4 + 0];
  const float by1 = bbox[n * 4 + 1];
  const float bx2 = bbox[n * 4 + 2];
  const float by2 = bbox[n * 4 + 3];
  const float xstep = (bx2 - bx1) * (1.0f / 14.0f);
  const float ystep = (by2 - by1) * (1.0f / 14.0f);

  // ---- row range touched by the 14 y samples (block-uniform) ----
  const int ylo = min(max((int)floorf(by1), 0), 31);
  const float ys13 = by1 + 13.0f * ystep;
  int yhi = min(min(max((int)floorf(ys13), 0), 31) + 1, 31);
  yhi = min(yhi, ylo + (RPAD - 1));         // defensive: never overflow plane
  const int R = yhi - ylo + 1;              // rows to stage (<= 22)

  // ---- coordinate tables, once per block ----
  if (t < 14) {
    float xs = bx1 + (float)t * xstep;
    int x0i = (int)fminf(fmaxf(floorf(xs), 0.0f), 31.0f);
    x0i = min(x0i, 30);                     // pair (x0,x0+1) valid (xs<31 anyway)
    sxa[t] = x0i;
    swx[t] = xs - (float)x0i;
  } else if (t < 28) {
    int g = t - 14;
    float yv = by1 + (float)g * ystep;
    float y0 = fminf(fmaxf(floorf(yv), 0.0f), 31.0f);
    int y0i = (int)y0;
    int y1i = min(y0i + 1, 31);
    y0i = min(max(y0i, ylo), yhi);
    y1i = min(max(y1i, ylo), yhi);
    sy0a[g] = (y0i - ylo) * STR;
    sy1a[g] = (y1i - ylo) * STR;
    swy[g] = yv - y0;
  }

  // ---- reg staging: wave stages 2 channels, all loads issued back-to-back ----
  const int rch = ln >> 3;                  // row within 8-row chunk
  const int q   = ln & 7;                   // float4 group within row
  const float* sb =
      feat + ((size_t)n * 256 + c0 + 2 * wv) * 1024 + (size_t)ylo * 32 + q * 4;
  float4 rgA[3], rgB[3];
#pragma unroll
  for (int k = 0; k < 3; ++k)
    if (k * 8 < R) {                        // block-uniform
      int srow = min(k * 8 + rch, R - 1);   // clamp tail (harmless dup fetch)
      rgA[k] = *(const float4*)(sb + srow * 32);
      rgB[k] = *(const float4*)(sb + 1024 + srow * 32);
    }
  {
    float* db = lds + 2 * wv * PLANE + q * 4;
#pragma unroll
    for (int k = 0; k < 3; ++k)
      if (k * 8 < R) {
        int drow = k * 8 + rch;
        if (drow < R) {                     // don't spill into next plane
          *(float4*)(db + drow * STR)         = rgA[k];
          *(float4*)(db + PLANE + drow * STR) = rgB[k];
        }
      }
  }
  __syncthreads();

  // ---- compute: lane s<49 -> one output of each of the wave's 2 channels ----
  if (ln < 49) {
    const int sy = ln / 7;                  // const divisor -> magic mul
    const int sx = ln - sy * 7;
    const float* plA = lds + 2 * wv * PLANE;
    const float* plB = plA + PLANE;
    float mA = -INFINITY, mB = -INFINITY;
#pragma unroll
    for (int i = 0; i < 2; ++i) {
      const int gy = 2 * sy + i;
      const int a0 = sy0a[gy];
      const int a1 = sy1a[gy];
      const float wy = swy[gy];
#pragma unroll
      for (int j = 0; j < 2; ++j) {
        const int gx = 2 * sx + j;
        const int x  = sxa[gx];
        const float wx = swx[gx];
        const float* pA0 = plA + a0 + x;    // -> ds_read2_b32 offset1:1
        const float* pA1 = plA + a1 + x;
        const float* pB0 = plB + a0 + x;
        const float* pB1 = plB + a1 + x;
        float vA00 = pA0[0], vA01 = pA0[1];
        float vA10 = pA1[0], vA11 = pA1[1];
        float vB00 = pB0[0], vB01 = pB0[1];
        float vB10 = pB1[0], vB11 = pB1[1];
        float tA = fmaf(wx, vA01 - vA00, vA00);
        float bA = fmaf(wx, vA11 - vA10, vA10);
        mA = fmaxf(mA, fmaf(wy, bA - tA, tA));
        float tB = fmaf(wx, vB01 - vB00, vB00);
        float bB = fmaf(wx, vB11 - vB10, vB10);
        mB = fmaxf(mB, fmaf(wy, bB - tB, tB));
      }
    }
    float* op = out + ((size_t)n * 256 + c0 + 2 * wv) * 49 + ln;
    op[0]  = mA;
    op[49] = mB;
  }
}

extern "C" void kernel_launch(void* const* d_in, const int* in_sizes, int n_in,
                              void* d_out, int out_size, void* d_ws, size_t ws_size,
                              hipStream_t stream) {
  const float* feat = (const float*)d_in[0];
  const float* bbox = (const float*)d_in[1];
  float* out = (float*)d_out;
  dim3 grid(512 * 32);                      // one block per (box, 8-channel group)
  roialign_kernel<<<grid, 256, 0, stream>>>(feat, bbox, out);
}

// Round 8
// 41.074 us; speedup vs baseline: 3.2481x; 2.8647x over previous
//
#include <hip/hip_runtime.h>
#include <math.h>

#define RPAD  24                 // row capacity (span guarantee <= 22), 8-row chunks
#define PLANE (RPAD * 32)        // 768 floats = 3 KB per channel plane
// Round-5 structure, ONE change: 2 channels per wave (8 per block).
// DMA global_load_lds (w=16) into LINEAR LDS; bank swizzle applied on the
// GLOBAL source group: LDS[yr][q] = G[srow][(q-yr)&7]; reads use (xg+yr)&7.
// Channel B lives at +PLANE (3072 B) -> same vaddr, immediate ds offset.
// LDS: 8 planes x 3 KB = 24 KB -> 6 blocks/CU (24 waves/CU).

typedef __attribute__((address_space(1))) const void gptr_t;
typedef __attribute__((address_space(3))) void lptr_t;

__global__ __launch_bounds__(256, 6) void roialign_kernel(
    const float* __restrict__ feat, const float* __restrict__ bbox,
    float* __restrict__ out) {
  __shared__ float lds[8 * PLANE];
  __shared__ int   sxg0[14], sxl0[14], sxg1[14], sxl1[14];  // x>>2, x&3
  __shared__ int   sy0r[14], sy1r[14];                      // row idx (y - ylo)
  __shared__ float swx[14], swy[14];

  const int blk = blockIdx.x;
  const int n  = blk >> 5;                   // 32 chunks of 8 channels per box
  const int c0 = (blk & 31) * 8;
  const int t  = threadIdx.x;
  const int wv = t >> 6;                     // wave owns channels c0+2wv, +1
  const int ln = t & 63;

  const float bx1 = bbox[n * 4 + 0];
  const float by1 = bbox[n * 4 + 1];
  const float bx2 = bbox[n * 4 + 2];
  const float by2 = bbox[n * 4 + 3];
  const float xstep = (bx2 - bx1) * (1.0f / 14.0f);
  const float ystep = (by2 - by1) * (1.0f / 14.0f);

  // ---- row range touched by the 14 y samples (block-uniform) ----
  const int ylo = min(max((int)floorf(by1), 0), 31);
  const float ys13 = by1 + 13.0f * ystep;
  int yhi = min(min(max((int)floorf(ys13), 0), 31) + 1, 31);
  yhi = min(yhi, ylo + (RPAD - 1));          // defensive: never overflow LDS
  const int R = yhi - ylo + 1;               // rows needed (<= 22)

  // ---- per-block coordinate tables (threads 0..27) ----
  if (t < 14) {
    float xs = bx1 + (float)t * xstep;
    float x0 = fminf(fmaxf(floorf(xs), 0.0f), 31.0f);
    int x0i = (int)x0;
    int x1i = min(x0i + 1, 31);
    sxg0[t] = x0i >> 2;
    sxl0[t] = x0i & 3;
    sxg1[t] = x1i >> 2;
    sxl1[t] = x1i & 3;
    swx[t] = xs - x0;
  } else if (t < 28) {
    int g = t - 14;
    float yv = by1 + (float)g * ystep;
    float y0 = fminf(fmaxf(floorf(yv), 0.0f), 31.0f);
    int y0i = (int)y0;
    int y1i = min(y0i + 1, 31);
    y0i = min(max(y0i, ylo), yhi);           // stays within staged span
    y1i = min(max(y1i, ylo), yhi);
    sy0r[g] = y0i - ylo;                     // row index within staged span
    sy1r[g] = y1i - ylo;
    swy[g] = yv - y0;
  }

  // ---- DMA staging: wave wv stages channels 2wv and 2wv+1 ----
  {
    const float* srcA =
        feat + ((size_t)n * 256 + c0 + 2 * wv) * 1024 + (size_t)ylo * 32;
    float* dstA = lds + 2 * wv * PLANE;
    const int rch = ln >> 3;                 // row within 8-row chunk
    const int q   = ln & 7;                  // dest float4 group
    for (int it = 0; it * 8 < R; ++it) {     // block-uniform trip count
      int yr   = it * 8 + rch;               // dest row
      int srow = min(yr, R - 1);             // clamp tail rows (dup fetch, L1 hit)
      int qp   = (q - yr) & 7;               // pre-swizzled source group
      const float* gpA = srcA + srow * 32 + qp * 4;
      lptr_t* lpA = (lptr_t*)(dstA + it * 256);         // wave-uniform dest
      __builtin_amdgcn_global_load_lds((gptr_t*)gpA, lpA, 16, 0, 0);
      const float* gpB = gpA + 1024;
      lptr_t* lpB = (lptr_t*)(dstA + PLANE + it * 256);
      __builtin_amdgcn_global_load_lds((gptr_t*)gpB, lpB, 16, 0, 0);
    }
  }
  asm volatile("s_waitcnt vmcnt(0)" ::: "memory");
  __syncthreads();

  // ---- compute: lane s<49 -> one output of each of the wave's 2 channels ----
  if (ln < 49) {
    const int sy = ln / 7;                   // const divisor -> magic mul
    const int sx = ln - sy * 7;
    const float* plane = lds + 2 * wv * PLANE;  // channel A; B at +PLANE
    float mA = -INFINITY, mB = -INFINITY;
#pragma unroll
    for (int i = 0; i < 2; ++i) {
      const int gy  = 2 * sy + i;
      const int yr0 = sy0r[gy];
      const int yr1 = sy1r[gy];
      const float wy = swy[gy];
      const float* r0 = plane + yr0 * 32;
      const float* r1 = plane + yr1 * 32;
#pragma unroll
      for (int j = 0; j < 2; ++j) {
        const int gx  = 2 * sx + j;
        const int xg0 = sxg0[gx], xl0 = sxl0[gx];
        const int xg1 = sxg1[gx], xl1 = sxl1[gx];
        const float wx = swx[gx];
        const int o00 = (((xg0 + yr0) & 7) << 2) + xl0;
        const int o01 = (((xg1 + yr0) & 7) << 2) + xl1;
        const int o10 = (((xg0 + yr1) & 7) << 2) + xl0;
        const int o11 = (((xg1 + yr1) & 7) << 2) + xl1;
        float vA00 = r0[o00], vB00 = r0[o00 + PLANE];   // B: offset:3072 imm
        float vA01 = r0[o01], vB01 = r0[o01 + PLANE];
        float vA10 = r1[o10], vB10 = r1[o10 + PLANE];
        float vA11 = r1[o11], vB11 = r1[o11 + PLANE];
        float tA = fmaf(wx, vA01 - vA00, vA00);
        float bA = fmaf(wx, vA11 - vA10, vA10);
        mA = fmaxf(mA, fmaf(wy, bA - tA, tA));
        float tB = fmaf(wx, vB01 - vB00, vB00);
        float bB = fmaf(wx, vB11 - vB10, vB10);
        mB = fmaxf(mB, fmaf(wy, bB - tB, tB));
      }
    }
    float* op = out + ((size_t)n * 256 + c0 + 2 * wv) * 49 + ln;
    op[0]  = mA;
    op[49] = mB;
  }
}

extern "C" void kernel_launch(void* const* d_in, const int* in_sizes, int n_in,
                              void* d_out, int out_size, void* d_ws, size_t ws_size,
                              hipStream_t stream) {
  const float* feat = (const float*)d_in[0];
  const float* bbox = (const float*)d_in[1];
  float* out = (float*)d_out;
  dim3 grid(512 * 32);                       // one block per (box, 8-channel group)
  roialign_kernel<<<grid, 256, 0, stream>>>(feat, bbox, out);
}

// Round 9
// 38.782 us; speedup vs baseline: 3.4400x; 1.0591x over previous
//
#include <hip/hip_runtime.h>
#include <math.h>

#define RPAD  24                 // row capacity (span guarantee <= 22), 8-row chunks
#define PLANE (RPAD * 32)        // 768 floats = 3 KB per channel plane
// r8 structure, ONE change: coordinate LDS tables removed — each compute lane
// derives its own sample coords in registers (trades ~16 divergent table
// ds_reads per wave-job for ~50 VALU; DS pipe is the modeled bottleneck).
// DMA global_load_lds (w=16) into LINEAR LDS; bank swizzle applied on the
// GLOBAL source group: LDS[yr][q] = G[srow][(q-yr)&7]; reads use (xg+yr)&7.
// LDS: 8 planes x 3 KB = 24 KB -> 6 blocks/CU (24 waves/CU).

typedef __attribute__((address_space(1))) const void gptr_t;
typedef __attribute__((address_space(3))) void lptr_t;

__global__ __launch_bounds__(256, 6) void roialign_kernel(
    const float* __restrict__ feat, const float* __restrict__ bbox,
    float* __restrict__ out) {
  __shared__ float lds[8 * PLANE];

  const int blk = blockIdx.x;
  const int n  = blk >> 5;                   // 32 chunks of 8 channels per box
  const int c0 = (blk & 31) * 8;
  const int t  = threadIdx.x;
  const int wv = t >> 6;                     // wave owns channels c0+2wv, +1
  const int ln = t & 63;

  const float bx1 = bbox[n * 4 + 0];
  const float by1 = bbox[n * 4 + 1];
  const float bx2 = bbox[n * 4 + 2];
  const float by2 = bbox[n * 4 + 3];
  const float xstep = (bx2 - bx1) * (1.0f / 14.0f);
  const float ystep = (by2 - by1) * (1.0f / 14.0f);

  // ---- row range touched by the 14 y samples (block-uniform) ----
  const int ylo = min(max((int)floorf(by1), 0), 31);
  const float ys13 = by1 + 13.0f * ystep;
  int yhi = min(min(max((int)floorf(ys13), 0), 31) + 1, 31);
  yhi = min(yhi, ylo + (RPAD - 1));          // defensive: never overflow LDS
  const int R = yhi - ylo + 1;               // rows needed (<= 22)

  // ---- DMA staging: wave wv stages channels 2wv and 2wv+1 ----
  {
    const float* srcA =
        feat + ((size_t)n * 256 + c0 + 2 * wv) * 1024 + (size_t)ylo * 32;
    float* dstA = lds + 2 * wv * PLANE;
    const int rch = ln >> 3;                 // row within 8-row chunk
    const int q   = ln & 7;                  // dest float4 group
    for (int it = 0; it * 8 < R; ++it) {     // block-uniform trip count
      int yr   = it * 8 + rch;               // dest row
      int srow = min(yr, R - 1);             // clamp tail rows (dup fetch, L1 hit)
      int qp   = (q - yr) & 7;               // pre-swizzled source group
      const float* gpA = srcA + srow * 32 + qp * 4;
      lptr_t* lpA = (lptr_t*)(dstA + it * 256);         // wave-uniform dest
      __builtin_amdgcn_global_load_lds((gptr_t*)gpA, lpA, 16, 0, 0);
      const float* gpB = gpA + 1024;
      lptr_t* lpB = (lptr_t*)(dstA + PLANE + it * 256);
      __builtin_amdgcn_global_load_lds((gptr_t*)gpB, lpB, 16, 0, 0);
    }
  }
  asm volatile("s_waitcnt vmcnt(0)" ::: "memory");
  __syncthreads();

  // ---- compute: lane s<49 -> one output of each of the wave's 2 channels ----
  if (ln < 49) {
    const int sy = ln / 7;                   // const divisor -> magic mul
    const int sx = ln - sy * 7;

    // per-lane coordinates in registers (formulas identical to r8's tables)
    int   xgv0[2], xlv0[2], xgv1[2], xlv1[2];
    float wxv[2];
    int   yr0v[2], yr1v[2];
    float wyv[2];
#pragma unroll
    for (int j = 0; j < 2; ++j) {
      float xs = bx1 + (float)(2 * sx + j) * xstep;
      float x0 = fminf(fmaxf(floorf(xs), 0.0f), 31.0f);
      int x0i = (int)x0;
      int x1i = min(x0i + 1, 31);
      xgv0[j] = x0i >> 2;
      xlv0[j] = x0i & 3;
      xgv1[j] = x1i >> 2;
      xlv1[j] = x1i & 3;
      wxv[j]  = xs - x0;
    }
#pragma unroll
    for (int i = 0; i < 2; ++i) {
      float yv = by1 + (float)(2 * sy + i) * ystep;
      float y0 = fminf(fmaxf(floorf(yv), 0.0f), 31.0f);
      int y0i = (int)y0;
      int y1i = min(y0i + 1, 31);
      y0i = min(max(y0i, ylo), yhi);         // stays within staged span
      y1i = min(max(y1i, ylo), yhi);
      yr0v[i] = y0i - ylo;                   // row index within staged span
      yr1v[i] = y1i - ylo;
      wyv[i]  = yv - y0;
    }

    const float* plane = lds + 2 * wv * PLANE;  // channel A; B at +PLANE
    float mA = -INFINITY, mB = -INFINITY;
#pragma unroll
    for (int i = 0; i < 2; ++i) {
      const int yr0 = yr0v[i];
      const int yr1 = yr1v[i];
      const float wy = wyv[i];
      const float* r0 = plane + yr0 * 32;
      const float* r1 = plane + yr1 * 32;
#pragma unroll
      for (int j = 0; j < 2; ++j) {
        const int xg0 = xgv0[j], xl0 = xlv0[j];
        const int xg1 = xgv1[j], xl1 = xlv1[j];
        const float wx = wxv[j];
        const int o00 = (((xg0 + yr0) & 7) << 2) + xl0;
        const int o01 = (((xg1 + yr0) & 7) << 2) + xl1;
        const int o10 = (((xg0 + yr1) & 7) << 2) + xl0;
        const int o11 = (((xg1 + yr1) & 7) << 2) + xl1;
        float vA00 = r0[o00], vB00 = r0[o00 + PLANE];   // B: offset:3072 imm
        float vA01 = r0[o01], vB01 = r0[o01 + PLANE];
        float vA10 = r1[o10], vB10 = r1[o10 + PLANE];
        float vA11 = r1[o11], vB11 = r1[o11 + PLANE];
        float tA = fmaf(wx, vA01 - vA00, vA00);
        float bA = fmaf(wx, vA11 - vA10, vA10);
        mA = fmaxf(mA, fmaf(wy, bA - tA, tA));
        float tB = fmaf(wx, vB01 - vB00, vB00);
        float bB = fmaf(wx, vB11 - vB10, vB10);
        mB = fmaxf(mB, fmaf(wy, bB - tB, tB));
      }
    }
    float* op = out + ((size_t)n * 256 + c0 + 2 * wv) * 49 + ln;
    op[0]  = mA;
    op[49] = mB;
  }
}

extern "C" void kernel_launch(void* const* d_in, const int* in_sizes, int n_in,
                              void* d_out, int out_size, void* d_ws, size_t ws_size,
                              hipStream_t stream) {
  const float* feat = (const float*)d_in[0];
  const float* bbox = (const float*)d_in[1];
  float* out = (float*)d_out;
  dim3 grid(512 * 32);                       // one block per (box, 8-channel group)
  roialign_kernel<<<grid, 256, 0, stream>>>(feat, bbox, out);
}